// Round 3
// baseline (187.947 us; speedup 1.0000x reference)
//
#include <hip/hip_runtime.h>
#include <math.h>

#define C 100
#define RPP 8                        // rows per pass per wave
#define PASSES 2
#define WAVES 4                      // waves per 256-thread block
#define ROWS_PER_BLOCK (WAVES * PASSES * RPP)   // 64
#define INV_NORM 0.3989422804014327f // 1/sqrt(2*pi), STD = 1
#define TBL_N 214                    // ws floats: [0,100) Atab, [100,200) cinv,
                                     // [200,213) w'(d), d=-6..6, [213] wfar

// --- setup: per-label tables, once per launch (d_ws is re-poisoned) ---
// target t_j = w(j-mu)/csum(mu), w(d) = exp(code(d) - inv_norm),
// code(d) = inv_norm * exp(-d^2/2)  (max code = inv_norm, at d=0)
// Atab[mu] = sum t log t = dotc/csum - inv_norm - log(csum)
// For |d|>=6: w(d) = wfar*(1+code), code<2e-8 -> w' = w - wfar ~ 0.
// So dot = sum_j w(j-mu) s_j = wfar*rowsum + sum_j w'[clamp(j-mu,-6,6)] s_j.
__global__ void kl_setup(float* __restrict__ tbl)
{
    int tid = threadIdx.x;
    if (tid < 13) {
        float d = (float)(tid - 6);
        float code = INV_NORM * expf(-0.5f * d * d);
        tbl[200 + tid] = expf(code - INV_NORM) - expf(-INV_NORM);
    } else if (tid == 13) {
        tbl[213] = expf(-INV_NORM);
    }
    if (tid < C) {
        float csum = 0.f, dotc = 0.f;
        for (int j = 0; j < C; ++j) {
            float d = (float)(j - tid);
            float code = INV_NORM * expf(-0.5f * d * d);
            float w = expf(code - INV_NORM);
            csum += w;
            dotc += w * code;
        }
        tbl[tid]       = dotc / csum - INV_NORM - logf(csum);  // Atab
        tbl[100 + tid] = 1.0f / csum;                          // cinv
    }
}

// --- main: wave-local tiles, no block barrier in the hot path ---
// kl_row = Atab[mu] + log(sum exp s) - cinv[mu]*(wfar*rowsum + sum w' s)
// (scores ~ N(0,1): exp(s) safe in fp32 without max-subtraction)
__global__ __launch_bounds__(256, 8) void kl_main(
    const float* __restrict__ scores,
    const int*   __restrict__ labels,
    const float* __restrict__ tbl,
    float* __restrict__ out, int n, float inv_n)
{
    __shared__ float slice[WAVES][RPP * C];   // 4 x 3200 B, wave-private
    __shared__ float ltab[TBL_N];
    __shared__ float wpart[WAVES];

    const int tid    = threadIdx.x;
    const int wave   = tid >> 6;
    const int lane   = tid & 63;
    const int subrow = lane >> 3;   // 0..7  (row within pass)
    const int sub    = lane & 7;    // 0..7  (lane within row)

    if (tid < TBL_N) ltab[tid] = tbl[tid];
    __syncthreads();                 // tables ready; slices are wave-private

    float* mys = slice[wave];
    const float* wt   = &ltab[200 + 6];   // wt[d], d in [-6,6]
    const float  wfar = ltab[213];

    const int waveRow0 = blockIdx.x * ROWS_PER_BLOCK + wave * (PASSES * RPP);
    float acc = 0.f;

    for (int pass = 0; pass < PASSES; ++pass) {
        const int rowBase = waveRow0 + pass * RPP;
        const int remRows = min(RPP, max(0, n - rowBase));
        const int nf4     = remRows * (C / 4);            // <= 200

        // load 8 rows = 200 float4, lane-contiguous (1 KB / instruction)
        const float4* gsrc = (const float4*)(scores + (size_t)rowBase * C);
        float4 v[4];
        #pragma unroll
        for (int c = 0; c < 4; ++c) {
            int g = lane + 64 * c;
            v[c] = (g < nf4) ? gsrc[g]
                             : make_float4(-87.f, -87.f, -87.f, -87.f);
        }
        const int myrow = rowBase + subrow;
        const int mu    = (myrow < n) ? labels[myrow] : 0;

        // flat contiguous LDS write: conflict-free ds_write_b128
        float4* st = (float4*)mys;
        #pragma unroll
        for (int c = 0; c < 4; ++c) {
            int g = lane + 64 * c;
            if (g < RPP * C / 4) st[g] = v[c];
        }
        // wave-synchronous: compiler inserts lgkmcnt; no __syncthreads needed

        // compute: 8 lanes/row, interleaved j = sub + 8i
        const float* sp = &mys[subrow * C + sub];
        const int dbase = sub - mu;
        float se = 0.f, rsum = 0.f, dot = 0.f;
        #pragma unroll
        for (int i = 0; i < 12; ++i) {
            float s = sp[8 * i];
            se  += __expf(s);
            rsum += s;
            int dcl = min(max(dbase + 8 * i, -6), 6);
            dot = fmaf(wt[dcl], s, dot);
        }
        if (sub < 4) {                 // tail element j = sub + 96 < 100
            float s = sp[96];
            se  += __expf(s);
            rsum += s;
            int dcl = min(max(dbase + 96, -6), 6);
            dot = fmaf(wt[dcl], s, dot);
        }
        float dv = fmaf(wfar, rsum, dot);

        // reduce over the 8 lanes of this row
        se += __shfl_xor(se, 1, 8); dv += __shfl_xor(dv, 1, 8);
        se += __shfl_xor(se, 2, 8); dv += __shfl_xor(dv, 2, 8);
        se += __shfl_xor(se, 4, 8); dv += __shfl_xor(dv, 4, 8);

        if (sub == 0 && myrow < n)
            acc += ltab[mu] + __logf(se) - ltab[100 + mu] * dv;
    }

    // wave reduce + block combine: one atomic per block
    #pragma unroll
    for (int off = 32; off > 0; off >>= 1)
        acc += __shfl_xor(acc, off, 64);
    if (lane == 0) wpart[wave] = acc;
    __syncthreads();
    if (tid == 0)
        atomicAdd(out, (wpart[0] + wpart[1] + wpart[2] + wpart[3]) * inv_n);
}

extern "C" void kernel_launch(void* const* d_in, const int* in_sizes, int n_in,
                              void* d_out, int out_size, void* d_ws, size_t ws_size,
                              hipStream_t stream)
{
    const float* scores = (const float*)d_in[0];
    const int*   labels = (const int*)d_in[1];
    float*       tbl    = (float*)d_ws;
    float*       out    = (float*)d_out;

    int n = in_sizes[0] / C;   // 262144

    hipMemsetAsync(d_out, 0, sizeof(float) * (size_t)out_size, stream);
    kl_setup<<<1, 128, 0, stream>>>(tbl);

    int blocks = (n + ROWS_PER_BLOCK - 1) / ROWS_PER_BLOCK;   // 4096
    kl_main<<<blocks, 256, 0, stream>>>(scores, labels, tbl, out, n,
                                        1.0f / (float)n);
}

// Round 4
// 159.127 us; speedup vs baseline: 1.1811x; 1.1811x over previous
//
#include <hip/hip_runtime.h>
#include <math.h>

#define C 100
#define RPP 16                        // rows per wave-pass
#define WAVES 4                       // waves per 256-thread block
#define PASSES 4                      // grid-strided passes per wave
#define ROWS_PER_BLOCK_PASS (WAVES * RPP)     // 64
#define INV_NORM 0.3989422804014327f  // 1/sqrt(2*pi), STD = 1
#define DMAX 6                        // |d|>6 -> w(d)-wfar < 5e-9 (negligible)

// quad-permute swizzles (within 4-lane groups): xor1 = [1,0,3,2], xor2 = [2,3,0,1]
#define QSWZ(x, pat) __int_as_float(__builtin_amdgcn_ds_swizzle(__float_as_int(x), (pat)))

// Math: target t_j = w(j-mu)/csum, w(d) = exp(code(d)-inv_norm),
//       code(d) = inv_norm*exp(-d^2/2), wfar = exp(-inv_norm) = lim_{|d|->inf} w.
// With w'(d) = w(d)-wfar (zero for |d|>6):
//   csum = 100*wfar + sum_{valid d} w'(d)
//   dot  = sum_j w(j-mu) s_j = wfar*rowsum + sum_{valid d} w'(d) s_{mu+d}
//   dotc = sum_j w(j-mu) code(j-mu) ~= sum_{valid d} w(d) code(d)
//   kl_row = dotc/csum - inv_norm - log(csum) + log(sum_j exp s_j) - dot/csum
// (scores ~ N(0,1): exp(s) safe in fp32 without max-subtraction)
__global__ __launch_bounds__(256, 6) void kl_main(
    const float* __restrict__ scores,
    const int*   __restrict__ labels,
    float* __restrict__ out, int n, float inv_n)
{
    __shared__ float sl[WAVES][RPP * C];   // 4 x 6400 B, wave-private
    __shared__ float wpart[WAVES];

    const int tid  = threadIdx.x;
    const int wave = tid >> 6;
    const int lane = tid & 63;
    const int r    = lane >> 2;     // row within pass: 0..15
    const int sub  = lane & 3;      // quad lane: 0..3

    // per-thread constant windows (registers after unroll; ~40 ops, once)
    const float wfar = __expf(-INV_NORM);
    float wp[DMAX + 1], wcp[DMAX + 1];
    #pragma unroll
    for (int k = 0; k <= DMAX; ++k) {
        float code = INV_NORM * __expf(-0.5f * (float)(k * k));
        float w    = __expf(code - INV_NORM);
        wp[k]  = w - wfar;        // w'(|d|)
        wcp[k] = w * code;        // w(|d|)*code(|d|)
    }

    float* mys = sl[wave];
    float acc = 0.f;

    for (int pass = 0; pass < PASSES; ++pass) {
        const int rowBase = (blockIdx.x * PASSES + pass) * ROWS_PER_BLOCK_PASS
                          + wave * RPP;
        const int remRows = min(RPP, max(0, n - rowBase));
        const int nf4     = remRows * (C / 4);            // <= 400

        // 16 rows = 400 float4: 7 coalesced wave-loads, all in flight
        const float4* gsrc = (const float4*)(scores + (size_t)rowBase * C);
        float4 v[7];
        #pragma unroll
        for (int c = 0; c < 7; ++c) {
            int g = lane + 64 * c;
            v[c] = (g < nf4) ? gsrc[g] : make_float4(0.f, 0.f, 0.f, 0.f);
        }
        const int myrow = rowBase + r;
        const int mu    = (myrow < n) ? labels[myrow] : 0;

        // contiguous ds_write_b128 (conflict-free); wave-coherent, no barrier
        float4* st = (float4*)mys;
        #pragma unroll
        for (int c = 0; c < 7; ++c) {
            int g = lane + 64 * c;
            if (g < RPP * (C / 4)) st[g] = v[c];
        }

        // --- per-row compute: quad (4 lanes) per row ---
        const float* sp = &mys[r * C];

        // sum exp and rowsum: 25 contiguous elems per lane
        // bank(100r + 25*sub + i) spreads 64 lanes over 32 banks 2-way: free
        float se = 0.f, rs = 0.f;
        const float* spl = sp + sub * 25;
        #pragma unroll
        for (int i = 0; i < 25; ++i) {
            float s = spl[i];
            se += __expf(s);
            rs += s;
        }
        // quad reduce (2-level xor within quads; all 4 lanes get the sum)
        se += QSWZ(se, 0x80B1); rs += QSWZ(rs, 0x80B1);
        se += QSWZ(se, 0x804E); rs += QSWZ(rs, 0x804E);

        // 13-term window around mu (all 4 lanes redundantly; LDS broadcasts)
        float dotw = 0.f, csum = (float)C * wfar, dotc = 0.f;
        #pragma unroll
        for (int d = -DMAX; d <= DMAX; ++d) {
            int idx   = mu + d;
            bool ok   = (unsigned)idx < (unsigned)C;
            float s   = sp[min(max(idx, 0), C - 1)];
            int   a   = (d < 0) ? -d : d;
            float wv  = ok ? wp[a]  : 0.f;
            float wcv = ok ? wcp[a] : 0.f;
            dotw = fmaf(wv, s, dotw);
            csum += wv;
            dotc += wcv;
        }

        if (sub == 0 && myrow < n) {
            float rc  = 1.0f / csum;
            float dot = fmaf(wfar, rs, dotw);
            acc += (dotc - dot) * rc - INV_NORM - __logf(csum) + __logf(se);
        }
    }

    // wave reduce + block combine: one atomic per block
    #pragma unroll
    for (int off = 32; off > 0; off >>= 1)
        acc += __shfl_xor(acc, off, 64);
    if (lane == 0) wpart[wave] = acc;
    __syncthreads();
    if (tid == 0)
        atomicAdd(out, (wpart[0] + wpart[1] + wpart[2] + wpart[3]) * inv_n);
}

extern "C" void kernel_launch(void* const* d_in, const int* in_sizes, int n_in,
                              void* d_out, int out_size, void* d_ws, size_t ws_size,
                              hipStream_t stream)
{
    const float* scores = (const float*)d_in[0];
    const int*   labels = (const int*)d_in[1];
    float*       out    = (float*)d_out;

    int n = in_sizes[0] / C;   // 262144

    hipMemsetAsync(d_out, 0, sizeof(float) * (size_t)out_size, stream);

    int rows_per_block = PASSES * ROWS_PER_BLOCK_PASS;          // 256
    int blocks = (n + rows_per_block - 1) / rows_per_block;     // 1024
    kl_main<<<blocks, 256, 0, stream>>>(scores, labels, out, n, 1.0f / (float)n);
}